// Round 9
// baseline (265.042 us; speedup 1.0000x reference)
//
#include <hip/hip_runtime.h>
#include <math.h>

// Codebook argmin via fp16 MFMA: B=16, K=512, C=512, H=W=64.
// R3: K-SPLIT (256 clusters/block).  R4: parallel merge+recheck.
// R5: 4 blocks/CU.  R6/R7: single fp16 MFMA + MARGIN/fp64-recheck net.
// R8: coalesced recheck via transposed centers; codebook 91us, total 260.
// R9: (a) SUPERCHUNK: 32 channels per phase -> 16 phases (was 32): halves
// barrier/waitcnt overhead per unit work. Steady vmcnt: entry 8 (fx_cur),
// +4 stage, +8 xload -> vmcnt(12) xwrite -> compute -> vmcnt(8) barrier.
// (b) LAUNCH FUSION 5->3: transpose folded into prep_pack; merge folded
// into recheck (per-block local flag list, no global compaction).

#define NK   512
#define NC   512
#define NHW  4096
#define NPX  65536            // 16 * 4096 pixels
#define MARGIN 0.05f

typedef unsigned short u16;
typedef __attribute__((ext_vector_type(8)))  _Float16 half8;
typedef __attribute__((ext_vector_type(8)))  unsigned short ushort8;
typedef __attribute__((ext_vector_type(16))) float  f32x16;

__device__ __forceinline__ u16 f2h(float f) {
    return __builtin_bit_cast(u16, (_Float16)f);   // v_cvt_f16_f32, RN
}

// Pack cluster centers into fp16 MFMA A-operand fragment order, grouped by
// k-half; compute 0.5*c_sq (fp32) and exact fp64 c_sq; scatter the cct
// transpose (cct[c][k] = cc[k][c], 8 strided stores per lane).
// wcc layout: [chunk 32][half 2][unit 8][lane 64][8 fp16].
__global__ __launch_bounds__(64) void prep_pack(const float* __restrict__ cc,
                                                u16* __restrict__ wcc,
                                                float* __restrict__ shalf,
                                                double* __restrict__ csqd,
                                                float* __restrict__ cct) {
    const int k    = blockIdx.x;
    const int lane = threadIdx.x;      // 64 j-groups of 8 channels
    const int c0   = lane * 8;
    const float* row = cc + (size_t)k * NC + c0;
    ushort8 hi;
    double dsum = 0.0;
    #pragma unroll
    for (int i = 0; i < 8; ++i) {
        float v = row[i];
        dsum = fma((double)v, (double)v, dsum);
        hi[i] = f2h(v);
        cct[(size_t)(c0 + i) * NK + k] = v;      // transpose scatter
    }
    const int ch  = c0 >> 4;           // 16-channel chunk
    const int kh  = (c0 >> 3) & 1;     // which 8-chan octet of the chunk
    const int mtg = k >> 5;            // global m-tile 0..15
    const int h   = mtg >> 3;          // k-half
    const int mtl = mtg & 7;           // local m-tile 0..7
    const int ls  = (k & 31) + 32 * kh;
    *(ushort8*)(wcc + (((size_t)(ch * 2 + h) * 8 + mtl) * 64 + ls) * 8) = hi;
    #pragma unroll
    for (int off = 32; off > 0; off >>= 1) dsum += __shfl_down(dsum, off, 64);
    if (lane == 0) {
        csqd[k]  = dsum;
        shalf[k] = 0.5f * (float)dsum;
    }
}

__global__ __launch_bounds__(256, 4) void codebook_mfma(
        const float* __restrict__ x,
        const u16* __restrict__ wcc,
        const float* __restrict__ shalf,
        float* __restrict__ cbv,          // [2][NPX] best v per half
        float* __restrict__ csv,          // [2][NPX] second v per half
        int*   __restrict__ ckk)          // [2][NPX] best k (global) per half
{
    __shared__ __align__(16) u16 cs0[16 * 512];   // 16KB cluster frags, buf 0
    __shared__ __align__(16) u16 cs1[16 * 512];   // 16KB cluster frags, buf 1
    __shared__ __align__(16) u16 xs0[4 * 512];    // 4KB x frags, buf 0
    __shared__ __align__(16) u16 xs1[4 * 512];    // 4KB x frags, buf 1
    // total 40960B -> 4 blocks/CU (160KB exactly).

    const int tid  = threadIdx.x;
    const int w    = tid >> 6;
    const int lane = tid & 63;

    const int h   = blockIdx.x & 1;               // k-half
    const int gp0 = (blockIdx.x >> 1) * 64;       // pixel-group base
    const float* xb = x + (size_t)(gp0 >> 12) * (NC * NHW) + (gp0 & (NHW - 1));

    f32x16 acc[2][2] = {};

    // x staging assignment: pixel p, chunk-octet kh, j-quarter jq (4 channels)
    const int p   = tid & 63;
    const int xkh = w & 1;
    const int jq  = w >> 1;
    const int xoff = ((p >> 5) * 64 + ((p & 31) + 32 * xkh)) * 8 + jq * 4;
    const float* xp = xb + (size_t)(xkh * 8 + jq * 4) * NHW + p;

    float fxa[8], fxb[8];             // 2-deep superchunk x prefetch

    // 8 fp32 loads: 4 channels per sub-chunk x 2 sub-chunks
    auto xload = [&](float* fx, int sc) {
        const float* xc0 = xp + (size_t)(2 * sc) * 16 * NHW;
        const float* xc1 = xc0 + 16 * NHW;
        fx[0] = xc0[0]; fx[1] = xc0[NHW]; fx[2] = xc0[2 * NHW]; fx[3] = xc0[3 * NHW];
        fx[4] = xc1[0]; fx[5] = xc1[NHW]; fx[6] = xc1[2 * NHW]; fx[7] = xc1[3 * NHW];
    };
    auto xwrite = [&](const float* fx, u16* xs) {
        #pragma unroll
        for (int sub = 0; sub < 2; ++sub) {
            u16 h0 = f2h(fx[sub * 4 + 0]), h1 = f2h(fx[sub * 4 + 1]);
            u16 h2 = f2h(fx[sub * 4 + 2]), h3 = f2h(fx[sub * 4 + 3]);
            uint2 hv = make_uint2((unsigned)h0 | ((unsigned)h1 << 16),
                                  (unsigned)h2 | ((unsigned)h3 << 16));
            *(uint2*)&xs[sub * 1024 + xoff] = hv;
        }
    };
    // 16 units x 1KB = 16KB per superchunk; 4 gload_lds per wave.
    auto stage_cs = [&](int sc, u16* dst) {
        #pragma unroll
        for (int sub = 0; sub < 2; ++sub) {
            #pragma unroll
            for (int i = 0; i < 2; ++i) {
                const int u = w * 2 + i;
                const u16* g = wcc + ((((size_t)(2 * sc + sub) * 2 + h) * 8 + u) * 64 + lane) * 8;
                __builtin_amdgcn_global_load_lds(
                    (const __attribute__((address_space(1))) void*)g,
                    (__attribute__((address_space(3))) void*)(dst + (sub * 8 + u) * 512),
                    16, 0, 0);
            }
        }
    };
    auto compute = [&](const u16* csb, const u16* xsb) {
        __builtin_amdgcn_s_setprio(1);
        #pragma unroll
        for (int sub = 0; sub < 2; ++sub) {
            half8 bh[2];
            #pragma unroll
            for (int nt = 0; nt < 2; ++nt)
                bh[nt] = *(const half8*)&xsb[sub * 1024 + ((size_t)nt * 64 + lane) * 8];
            #pragma unroll
            for (int mtl2 = 0; mtl2 < 2; ++mtl2) {
                const int gm = w * 2 + mtl2;          // local m-tile 0..7
                half8 ah = *(const half8*)&csb[((size_t)(sub * 8 + gm) * 64 + lane) * 8];
                #pragma unroll
                for (int nt = 0; nt < 2; ++nt)
                    acc[mtl2][nt] = __builtin_amdgcn_mfma_f32_32x32x16_f16(ah, bh[nt], acc[mtl2][nt], 0, 0, 0);
            }
        }
        __builtin_amdgcn_s_setprio(0);
    };

    // Steady phase t: compute sc t (cur), stage sc t+1 (nxt), xload sc t+2.
    // Entry: fx_cur 8 outstanding. +4 stage -> 12; +8 xload -> 20.
    // vmcnt(12): fx_cur drained. vmcnt(8): stage drained, fx_nxt (8) stays
    // in flight ACROSS the barrier.
    auto phase = [&](int t, u16* cs_cur, u16* cs_nxt, u16* xs_cur, u16* xs_nxt,
                     float* fx_cur, float* fx_nxt) {
        stage_cs(t + 1, cs_nxt);
        __builtin_amdgcn_sched_barrier(0);
        xload(fx_nxt, t + 2);
        asm volatile("s_waitcnt vmcnt(12)" ::: "memory");
        xwrite(fx_cur, xs_nxt);
        compute(cs_cur, xs_cur);
        asm volatile("s_waitcnt vmcnt(8) lgkmcnt(0)" ::: "memory");
        __builtin_amdgcn_s_barrier();
        __builtin_amdgcn_sched_barrier(0);
    };

    // ---- prologue (no prior VMEM: counts clean) ----
    xload(fxa, 0);                                    // 8 (oldest)
    __builtin_amdgcn_sched_barrier(0);
    stage_cs(0, cs0);                                 // +4 -> 12
    __builtin_amdgcn_sched_barrier(0);
    xload(fxb, 1);                                    // +8 -> 20
    asm volatile("s_waitcnt vmcnt(12)" ::: "memory"); // fxa ready
    xwrite(fxa, xs0);
    asm volatile("s_waitcnt vmcnt(8) lgkmcnt(0)" ::: "memory"); // cs0 done
    __builtin_amdgcn_s_barrier();
    __builtin_amdgcn_sched_barrier(0);

    // ---- main loop: superchunks 0..13 ----
    for (int t = 0; t < 14; t += 2) {
        phase(t,     cs0, cs1, xs0, xs1, fxb, fxa);
        phase(t + 1, cs1, cs0, xs1, xs0, fxa, fxb);
    }

    // ---- tail: sc 14 computes, sc 15 staged ----
    stage_cs(15, cs1);                                // fxb(8) + 4 -> 12
    asm volatile("s_waitcnt vmcnt(4)" ::: "memory");  // fxb ready
    xwrite(fxb, xs1);
    compute(cs0, xs0);
    asm volatile("s_waitcnt vmcnt(0) lgkmcnt(0)" ::: "memory");
    __builtin_amdgcn_s_barrier();
    __builtin_amdgcn_sched_barrier(0);
    compute(cs1, xs1);
    __syncthreads();

    // ---- epilogue: per-half top-2 -> ws (overlays cs0, 7KB <= 16KB) ----
    float* cand_v = (float*)cs0;             // 2KB
    float* cand_s = cand_v + 512;            // 2KB
    int*   cand_k = (int*)(cand_s + 512);    // 2KB
    float* sh_ep  = (float*)(cand_k + 512);  // 1KB: 0.5*c_sq for this half

    sh_ep[tid] = shalf[h * 256 + tid];
    __syncthreads();

    const int qb = lane >> 5;
    #pragma unroll
    for (int nt = 0; nt < 2; ++nt) {
        float best = -INFINITY, sec = -INFINITY;
        int bk = 0;
        #pragma unroll
        for (int mtl2 = 0; mtl2 < 2; ++mtl2) {
            const int kbase = w * 64 + mtl2 * 32 + 4 * qb;
            #pragma unroll
            for (int reg = 0; reg < 16; ++reg) {
                const int k = kbase + (reg & 3) + 8 * (reg >> 2);  // ascending
                const float v = acc[mtl2][nt][reg] - sh_ep[k];
                if (v > best) { sec = best; best = v; bk = k; }
                else if (v > sec) sec = v;
            }
        }
        const int pc   = nt * 32 + (lane & 31);
        const int slot = w * 2 + qb;
        cand_v[pc * 8 + slot] = best;
        cand_s[pc * 8 + slot] = sec;
        cand_k[pc * 8 + slot] = bk;
    }
    __syncthreads();

    if (tid < 64) {
        float best = -INFINITY, sec = -INFINITY;
        int bk = 1 << 30;
        #pragma unroll
        for (int s = 0; s < 8; ++s) {
            float v  = cand_v[tid * 8 + s];
            float v2 = cand_s[tid * 8 + s];
            int  kk  = cand_k[tid * 8 + s];
            if (v > best || (v == best && kk < bk)) {
                sec = fmaxf(sec, best);
                best = v; bk = kk;
            } else sec = fmaxf(sec, v);
            sec = fmaxf(sec, v2);
        }
        const int gpx = gp0 + tid;
        cbv[h * NPX + gpx] = best;
        csv[h * NPX + gpx] = sec;
        ckk[h * NPX + gpx] = h * 256 + bk;
    }
}

// Fused merge + exact fp64 recheck. Block b owns pixels [b*64, b*64+64):
// merges the two k-halves, writes out, builds a LOCAL near-tie list, then
// rechecks its own flagged pixels 2 at a time (coalesced cct[c][k] stream;
// dist ordering = -2*cross + csqd, x_sq common; 8 independent fp64 chains).
__global__ __launch_bounds__(256) void merge_recheck(
        const float* __restrict__ x,
        const float* __restrict__ cct,     // [c][k] transposed centers
        const double* __restrict__ csqd,   // exact fp64 c_sq
        const float* __restrict__ cbv,
        const float* __restrict__ csv,
        const int*   __restrict__ ckk,
        int* __restrict__ out)
{
    __shared__ float  xcol[2][NC];            // 4KB
    __shared__ double part[2][4][NK];         // 32KB
    __shared__ double dvv[256];               // 2KB
    __shared__ int    dii[256];               // 1KB
    __shared__ int    list[64];
    __shared__ int    nflag;

    const int tid  = threadIdx.x;
    const int w    = tid >> 6;
    const int lane = tid & 63;
    const int pb   = blockIdx.x * 64;

    if (tid == 0) nflag = 0;
    __syncthreads();

    if (tid < 64) {
        const int px = pb + tid;
        const float b0 = cbv[px], b1 = cbv[NPX + px];
        const float s0 = csv[px], s1 = csv[NPX + px];
        const int   k0 = ckk[px], k1 = ckk[NPX + px];
        float best, sec; int bk;
        if (b0 >= b1) { best = b0; bk = k0; sec = fmaxf(s0, b1); }
        else          { best = b1; bk = k1; sec = fmaxf(s1, b0); }
        out[px] = bk;
        if (best - sec < MARGIN) { int i = atomicAdd(&nflag, 1); list[i] = px; }
    }
    __syncthreads();

    const int n = nflag;
    for (int idx = 0; idx < n; idx += 2) {
        const int px0 = list[idx];
        const int px1 = (idx + 1 < n) ? list[idx + 1] : px0;

        #pragma unroll
        for (int r = 0; r < 2; ++r) {
            const int c = tid + r * 256;
            xcol[0][c] = x[(size_t)(px0 >> 12) * (NC * NHW) + (size_t)c * NHW + (px0 & (NHW - 1))];
            xcol[1][c] = x[(size_t)(px1 >> 12) * (NC * NHW) + (size_t)c * NHW + (px1 & (NHW - 1))];
        }
        __syncthreads();

        double a0[8] = {}, a1[8] = {};
        const float4* cr = (const float4*)(cct + (size_t)(w * 128) * NK) + lane * 2;
        #pragma unroll 4
        for (int c0 = 0; c0 < 128; ++c0) {
            const float4 va = cr[0];
            const float4 vb = cr[1];
            cr += NK / 4;
            const double x0 = (double)xcol[0][w * 128 + c0];
            const double x1 = (double)xcol[1][w * 128 + c0];
            const double c4[8] = {(double)va.x, (double)va.y, (double)va.z, (double)va.w,
                                  (double)vb.x, (double)vb.y, (double)vb.z, (double)vb.w};
            #pragma unroll
            for (int j = 0; j < 8; ++j) {
                a0[j] = fma(x0, c4[j], a0[j]);
                a1[j] = fma(x1, c4[j], a1[j]);
            }
        }
        #pragma unroll
        for (int j = 0; j < 8; ++j) {
            part[0][w][lane * 8 + j] = a0[j];
            part[1][w][lane * 8 + j] = a1[j];
        }
        __syncthreads();

        #pragma unroll
        for (int pxi = 0; pxi < 2; ++pxi) {
            double bd = 1e300;
            int bkk = 1 << 30;
            #pragma unroll
            for (int r = 0; r < 2; ++r) {
                const int k = tid + r * 256;
                const double cross = part[pxi][0][k] + part[pxi][1][k]
                                   + part[pxi][2][k] + part[pxi][3][k];
                const double d = fma(-2.0, cross, csqd[k]);
                if (d < bd || (d == bd && k < bkk)) { bd = d; bkk = k; }
            }
            dvv[tid] = bd; dii[tid] = bkk;
            __syncthreads();
            for (int srd = 128; srd > 0; srd >>= 1) {
                if (tid < srd) {
                    double ov = dvv[tid + srd]; int oi = dii[tid + srd];
                    if (ov < dvv[tid] || (ov == dvv[tid] && oi < dii[tid])) {
                        dvv[tid] = ov; dii[tid] = oi;
                    }
                }
                __syncthreads();
            }
            if (tid == 0) out[pxi == 0 ? px0 : px1] = dii[0];
            __syncthreads();
        }
    }
}

extern "C" void kernel_launch(void* const* d_in, const int* in_sizes, int n_in,
                              void* d_out, int out_size, void* d_ws, size_t ws_size,
                              hipStream_t stream) {
    const float* x  = (const float*)d_in[0];   // (16, 512, 64, 64) f32
    const float* cc = (const float*)d_in[1];   // (1, 512, 512, 1, 1) f32 -> [k][c]
    int* out = (int*)d_out;                    // (16, 1, 64, 64) int32

    double* csqd  = (double*)d_ws;                        // 512 doubles (4KB)
    float*  shalf = (float*)(csqd + NK);                  // 512 floats (2KB)
    u16*    wcc   = (u16*)(shalf + NK);                   // 512KB frag-ordered fp16
    float*  cct   = (float*)(wcc + 32 * 2 * 8 * 64 * 8);  // 1MB transposed centers
    float*  cbv   = cct + (size_t)NC * NK;                // 2*NPX floats
    float*  csv   = cbv + 2 * NPX;                        // 2*NPX floats
    int*    ckk   = (int*)(csv + 2 * NPX);                // 2*NPX ints

    prep_pack<<<NK, 64, 0, stream>>>(cc, wcc, shalf, csqd, cct);
    codebook_mfma<<<(NPX / 64) * 2, 256, 0, stream>>>(x, wcc, shalf, cbv, csv, ckk);
    merge_recheck<<<NPX / 64, 256, 0, stream>>>(x, cct, csqd, cbv, csv, ckk, out);
}

// Round 10
// 250.944 us; speedup vs baseline: 1.0562x; 1.0562x over previous
//
#include <hip/hip_runtime.h>
#include <math.h>

// Codebook argmin via fp16 MFMA: B=16, K=512, C=512, H=W=64.
// R3: K-SPLIT (256 clusters/block).  R4: parallel merge+recheck.
// R5: 4 blocks/CU.  R6/R7: single fp16 MFMA + MARGIN/fp64-recheck net.
// R8: coalesced recheck (transposed centers).  R9: superchunk (codebook 81us)
// but merge_recheck fusion lost to load imbalance (~64us tail).
// R10: three-stage tail. merge: global compaction (balanced). recheck32:
// 4 px per cct stream, lanes own 8 k, fp32-fma refine (sigma ~1e-5); gap <
// GATE2=1e-3 (~100 sigma) -> list2. recheck64: fp64 full rescan of list2
// (~100 px) -- final authority. Codebook/prep unchanged.

#define NK   512
#define NC   512
#define NHW  4096
#define NPX  65536            // 16 * 4096 pixels
#define MARGIN 0.05f
#define GATE2  1e-3f

typedef unsigned short u16;
typedef __attribute__((ext_vector_type(8)))  _Float16 half8;
typedef __attribute__((ext_vector_type(8)))  unsigned short ushort8;
typedef __attribute__((ext_vector_type(16))) float  f32x16;

__device__ __forceinline__ u16 f2h(float f) {
    return __builtin_bit_cast(u16, (_Float16)f);   // v_cvt_f16_f32, RN
}

// Pack cluster centers into fp16 MFMA A-operand fragment order, grouped by
// k-half; compute 0.5*c_sq (fp32), exact fp64 c_sq (+fp32 copy); scatter the
// cct transpose. Zero both flag counters.
// wcc layout: [chunk 32][half 2][unit 8][lane 64][8 fp16].
__global__ __launch_bounds__(64) void prep_pack(const float* __restrict__ cc,
                                                u16* __restrict__ wcc,
                                                float* __restrict__ shalf,
                                                double* __restrict__ csqd,
                                                float* __restrict__ csqf,
                                                float* __restrict__ cct,
                                                int* __restrict__ gcnt,
                                                int* __restrict__ gcnt2) {
    const int k    = blockIdx.x;
    const int lane = threadIdx.x;      // 64 j-groups of 8 channels
    if (k == 0 && lane == 0) { gcnt[0] = 0; gcnt2[0] = 0; }
    const int c0   = lane * 8;
    const float* row = cc + (size_t)k * NC + c0;
    ushort8 hi;
    double dsum = 0.0;
    #pragma unroll
    for (int i = 0; i < 8; ++i) {
        float v = row[i];
        dsum = fma((double)v, (double)v, dsum);
        hi[i] = f2h(v);
        cct[(size_t)(c0 + i) * NK + k] = v;      // transpose scatter
    }
    const int ch  = c0 >> 4;           // 16-channel chunk
    const int kh  = (c0 >> 3) & 1;     // which 8-chan octet of the chunk
    const int mtg = k >> 5;            // global m-tile 0..15
    const int h   = mtg >> 3;          // k-half
    const int mtl = mtg & 7;           // local m-tile 0..7
    const int ls  = (k & 31) + 32 * kh;
    *(ushort8*)(wcc + (((size_t)(ch * 2 + h) * 8 + mtl) * 64 + ls) * 8) = hi;
    #pragma unroll
    for (int off = 32; off > 0; off >>= 1) dsum += __shfl_down(dsum, off, 64);
    if (lane == 0) {
        csqd[k]  = dsum;
        csqf[k]  = (float)dsum;
        shalf[k] = 0.5f * (float)dsum;
    }
}

__global__ __launch_bounds__(256, 4) void codebook_mfma(
        const float* __restrict__ x,
        const u16* __restrict__ wcc,
        const float* __restrict__ shalf,
        float* __restrict__ cbv,          // [2][NPX] best v per half
        float* __restrict__ csv,          // [2][NPX] second v per half
        int*   __restrict__ ckk)          // [2][NPX] best k (global) per half
{
    __shared__ __align__(16) u16 cs0[16 * 512];   // 16KB cluster frags, buf 0
    __shared__ __align__(16) u16 cs1[16 * 512];   // 16KB cluster frags, buf 1
    __shared__ __align__(16) u16 xs0[4 * 512];    // 4KB x frags, buf 0
    __shared__ __align__(16) u16 xs1[4 * 512];    // 4KB x frags, buf 1
    // total 40960B -> 4 blocks/CU (160KB exactly).

    const int tid  = threadIdx.x;
    const int w    = tid >> 6;
    const int lane = tid & 63;

    const int h   = blockIdx.x & 1;               // k-half
    const int gp0 = (blockIdx.x >> 1) * 64;       // pixel-group base
    const float* xb = x + (size_t)(gp0 >> 12) * (NC * NHW) + (gp0 & (NHW - 1));

    f32x16 acc[2][2] = {};

    // x staging assignment: pixel p, chunk-octet kh, j-quarter jq (4 channels)
    const int p   = tid & 63;
    const int xkh = w & 1;
    const int jq  = w >> 1;
    const int xoff = ((p >> 5) * 64 + ((p & 31) + 32 * xkh)) * 8 + jq * 4;
    const float* xp = xb + (size_t)(xkh * 8 + jq * 4) * NHW + p;

    float fxa[8], fxb[8];             // 2-deep superchunk x prefetch

    // 8 fp32 loads: 4 channels per sub-chunk x 2 sub-chunks
    auto xload = [&](float* fx, int sc) {
        const float* xc0 = xp + (size_t)(2 * sc) * 16 * NHW;
        const float* xc1 = xc0 + 16 * NHW;
        fx[0] = xc0[0]; fx[1] = xc0[NHW]; fx[2] = xc0[2 * NHW]; fx[3] = xc0[3 * NHW];
        fx[4] = xc1[0]; fx[5] = xc1[NHW]; fx[6] = xc1[2 * NHW]; fx[7] = xc1[3 * NHW];
    };
    auto xwrite = [&](const float* fx, u16* xs) {
        #pragma unroll
        for (int sub = 0; sub < 2; ++sub) {
            u16 h0 = f2h(fx[sub * 4 + 0]), h1 = f2h(fx[sub * 4 + 1]);
            u16 h2 = f2h(fx[sub * 4 + 2]), h3 = f2h(fx[sub * 4 + 3]);
            uint2 hv = make_uint2((unsigned)h0 | ((unsigned)h1 << 16),
                                  (unsigned)h2 | ((unsigned)h3 << 16));
            *(uint2*)&xs[sub * 1024 + xoff] = hv;
        }
    };
    // 16 units x 1KB = 16KB per superchunk; 4 gload_lds per wave.
    auto stage_cs = [&](int sc, u16* dst) {
        #pragma unroll
        for (int sub = 0; sub < 2; ++sub) {
            #pragma unroll
            for (int i = 0; i < 2; ++i) {
                const int u = w * 2 + i;
                const u16* g = wcc + ((((size_t)(2 * sc + sub) * 2 + h) * 8 + u) * 64 + lane) * 8;
                __builtin_amdgcn_global_load_lds(
                    (const __attribute__((address_space(1))) void*)g,
                    (__attribute__((address_space(3))) void*)(dst + (sub * 8 + u) * 512),
                    16, 0, 0);
            }
        }
    };
    auto compute = [&](const u16* csb, const u16* xsb) {
        __builtin_amdgcn_s_setprio(1);
        #pragma unroll
        for (int sub = 0; sub < 2; ++sub) {
            half8 bh[2];
            #pragma unroll
            for (int nt = 0; nt < 2; ++nt)
                bh[nt] = *(const half8*)&xsb[sub * 1024 + ((size_t)nt * 64 + lane) * 8];
            #pragma unroll
            for (int mtl2 = 0; mtl2 < 2; ++mtl2) {
                const int gm = w * 2 + mtl2;          // local m-tile 0..7
                half8 ah = *(const half8*)&csb[((size_t)(sub * 8 + gm) * 64 + lane) * 8];
                #pragma unroll
                for (int nt = 0; nt < 2; ++nt)
                    acc[mtl2][nt] = __builtin_amdgcn_mfma_f32_32x32x16_f16(ah, bh[nt], acc[mtl2][nt], 0, 0, 0);
            }
        }
        __builtin_amdgcn_s_setprio(0);
    };

    // Steady phase t: compute sc t (cur), stage sc t+1 (nxt), xload sc t+2.
    // Entry: fx_cur 8 outstanding. +4 stage -> 12; +8 xload -> 20.
    // vmcnt(12): fx_cur drained. vmcnt(8): stage drained, fx_nxt (8) stays
    // in flight ACROSS the barrier.
    auto phase = [&](int t, u16* cs_cur, u16* cs_nxt, u16* xs_cur, u16* xs_nxt,
                     float* fx_cur, float* fx_nxt) {
        stage_cs(t + 1, cs_nxt);
        __builtin_amdgcn_sched_barrier(0);
        xload(fx_nxt, t + 2);
        asm volatile("s_waitcnt vmcnt(12)" ::: "memory");
        xwrite(fx_cur, xs_nxt);
        compute(cs_cur, xs_cur);
        asm volatile("s_waitcnt vmcnt(8) lgkmcnt(0)" ::: "memory");
        __builtin_amdgcn_s_barrier();
        __builtin_amdgcn_sched_barrier(0);
    };

    // ---- prologue (no prior VMEM: counts clean) ----
    xload(fxa, 0);                                    // 8 (oldest)
    __builtin_amdgcn_sched_barrier(0);
    stage_cs(0, cs0);                                 // +4 -> 12
    __builtin_amdgcn_sched_barrier(0);
    xload(fxb, 1);                                    // +8 -> 20
    asm volatile("s_waitcnt vmcnt(12)" ::: "memory"); // fxa ready
    xwrite(fxa, xs0);
    asm volatile("s_waitcnt vmcnt(8) lgkmcnt(0)" ::: "memory"); // cs0 done
    __builtin_amdgcn_s_barrier();
    __builtin_amdgcn_sched_barrier(0);

    // ---- main loop: superchunks 0..13 ----
    for (int t = 0; t < 14; t += 2) {
        phase(t,     cs0, cs1, xs0, xs1, fxb, fxa);
        phase(t + 1, cs1, cs0, xs1, xs0, fxa, fxb);
    }

    // ---- tail: sc 14 computes, sc 15 staged ----
    stage_cs(15, cs1);                                // fxb(8) + 4 -> 12
    asm volatile("s_waitcnt vmcnt(4)" ::: "memory");  // fxb ready
    xwrite(fxb, xs1);
    compute(cs0, xs0);
    asm volatile("s_waitcnt vmcnt(0) lgkmcnt(0)" ::: "memory");
    __builtin_amdgcn_s_barrier();
    __builtin_amdgcn_sched_barrier(0);
    compute(cs1, xs1);
    __syncthreads();

    // ---- epilogue: per-half top-2 -> ws (overlays cs0, 7KB <= 16KB) ----
    float* cand_v = (float*)cs0;             // 2KB
    float* cand_s = cand_v + 512;            // 2KB
    int*   cand_k = (int*)(cand_s + 512);    // 2KB
    float* sh_ep  = (float*)(cand_k + 512);  // 1KB: 0.5*c_sq for this half

    sh_ep[tid] = shalf[h * 256 + tid];
    __syncthreads();

    const int qb = lane >> 5;
    #pragma unroll
    for (int nt = 0; nt < 2; ++nt) {
        float best = -INFINITY, sec = -INFINITY;
        int bk = 0;
        #pragma unroll
        for (int mtl2 = 0; mtl2 < 2; ++mtl2) {
            const int kbase = w * 64 + mtl2 * 32 + 4 * qb;
            #pragma unroll
            for (int reg = 0; reg < 16; ++reg) {
                const int k = kbase + (reg & 3) + 8 * (reg >> 2);  // ascending
                const float v = acc[mtl2][nt][reg] - sh_ep[k];
                if (v > best) { sec = best; best = v; bk = k; }
                else if (v > sec) sec = v;
            }
        }
        const int pc   = nt * 32 + (lane & 31);
        const int slot = w * 2 + qb;
        cand_v[pc * 8 + slot] = best;
        cand_s[pc * 8 + slot] = sec;
        cand_k[pc * 8 + slot] = bk;
    }
    __syncthreads();

    if (tid < 64) {
        float best = -INFINITY, sec = -INFINITY;
        int bk = 1 << 30;
        #pragma unroll
        for (int s = 0; s < 8; ++s) {
            float v  = cand_v[tid * 8 + s];
            float v2 = cand_s[tid * 8 + s];
            int  kk  = cand_k[tid * 8 + s];
            if (v > best || (v == best && kk < bk)) {
                sec = fmaxf(sec, best);
                best = v; bk = kk;
            } else sec = fmaxf(sec, v);
            sec = fmaxf(sec, v2);
        }
        const int gpx = gp0 + tid;
        cbv[h * NPX + gpx] = best;
        csv[h * NPX + gpx] = sec;
        ckk[h * NPX + gpx] = h * 256 + bk;
    }
}

// Per-pixel merge of the two k-halves; writes out; compacts near-tie pixels
// into a global list for the staged recheck.
__global__ __launch_bounds__(256) void merge(
        const float* __restrict__ cbv,
        const float* __restrict__ csv,
        const int*   __restrict__ ckk,
        int* __restrict__ out,
        int* __restrict__ glist,
        int* __restrict__ gcnt)
{
    const int px = blockIdx.x * 256 + threadIdx.x;

    const float b0 = cbv[px],        b1 = cbv[NPX + px];
    const float s0 = csv[px],        s1 = csv[NPX + px];
    const int   k0 = ckk[px],        k1 = ckk[NPX + px];

    float best, sec; int bk;
    if (b0 >= b1) { best = b0; bk = k0; sec = fmaxf(s0, b1); }
    else          { best = b1; bk = k1; sec = fmaxf(s1, b0); }

    out[px] = bk;
    if (best - sec < MARGIN) {
        int i = atomicAdd(gcnt, 1);
        glist[i] = px;
    }
}

// Stage-2: fp32-fma refine, 4 pixels per cct stream. Lane owns 8 clusters
// (k = lane*8..+7, 2 coalesced float4); wave w covers c-quarter. d ordering
// = -2*cross + csqf (x_sq common). Gap < GATE2 escalates to list2.
__global__ __launch_bounds__(256, 3) void recheck32(
        const float* __restrict__ x,
        const float* __restrict__ cct,
        const float* __restrict__ csqf,
        const int*   __restrict__ glist,
        const int*   __restrict__ gcnt,
        int* __restrict__ out,
        int* __restrict__ list2,
        int* __restrict__ gcnt2)
{
    __shared__ float xq[NC][4];        // 8KB, xq[c][px]
    __shared__ float part[4][4][NK];   // 32KB, part[px][w][k]
    __shared__ float dvv[256];         // best
    __shared__ float dsv[256];         // second
    __shared__ int   dii[256];

    const int tid  = threadIdx.x;
    const int w    = tid >> 6;
    const int lane = tid & 63;
    const int n    = gcnt[0];
    const int npass = (n + 3) >> 2;

    for (int ps = blockIdx.x; ps < npass; ps += gridDim.x) {
        int pxid[4];
        #pragma unroll
        for (int j = 0; j < 4; ++j) {
            int i = ps * 4 + j;
            pxid[j] = glist[i < n ? i : n - 1];
        }
        // stage xq (gathered; 8 independent loads/thread)
        #pragma unroll
        for (int r = 0; r < 8; ++r) {
            const int linear = r * 256 + tid;
            const int c = linear >> 2, j = linear & 3;
            const int px = pxid[j];
            xq[c][j] = x[(size_t)(px >> 12) * (NC * NHW) + (size_t)c * NHW + (px & (NHW - 1))];
        }
        __syncthreads();

        float a[4][8] = {};
        const float4* cp = (const float4*)(cct + (size_t)(w * 128) * NK) + lane * 2;
        for (int c0 = 0; c0 < 128; ++c0) {
            const float4 cv0 = cp[0];
            const float4 cv1 = cp[1];
            cp += NK / 4;
            const float4 xv = *(const float4*)&xq[w * 128 + c0][0];   // broadcast
            const float ck[8] = {cv0.x, cv0.y, cv0.z, cv0.w, cv1.x, cv1.y, cv1.z, cv1.w};
            const float xs4[4] = {xv.x, xv.y, xv.z, xv.w};
            #pragma unroll
            for (int j = 0; j < 4; ++j)
                #pragma unroll
                for (int q = 0; q < 8; ++q)
                    a[j][q] = fmaf(xs4[j], ck[q], a[j][q]);
        }
        #pragma unroll
        for (int j = 0; j < 4; ++j)
            #pragma unroll
            for (int q = 0; q < 8; ++q)
                part[j][w][lane * 8 + q] = a[j][q];
        __syncthreads();

        #pragma unroll
        for (int j = 0; j < 4; ++j) {
            float bd = 1e30f, sd = 1e30f;
            int bi = 1 << 30;
            #pragma unroll
            for (int r = 0; r < 2; ++r) {
                const int k = tid + r * 256;
                const float cross = part[j][0][k] + part[j][1][k]
                                  + part[j][2][k] + part[j][3][k];
                const float d = fmaf(-2.f, cross, csqf[k]);
                if (d < bd || (d == bd && k < bi)) { sd = bd; bd = d; bi = k; }
                else sd = fminf(sd, d);
            }
            dvv[tid] = bd; dsv[tid] = sd; dii[tid] = bi;
            __syncthreads();
            for (int s = 128; s > 0; s >>= 1) {
                if (tid < s) {
                    const float ov = dvv[tid + s], os = dsv[tid + s];
                    const int oi = dii[tid + s];
                    if (ov < dvv[tid] || (ov == dvv[tid] && oi < dii[tid])) {
                        dsv[tid] = fminf(dvv[tid], fminf(os, dsv[tid]));
                        dvv[tid] = ov; dii[tid] = oi;
                    } else {
                        dsv[tid] = fminf(dsv[tid], fminf(ov, os));
                    }
                }
                __syncthreads();
            }
            if (tid == 0) {
                out[pxid[j]] = dii[0];
                if (dsv[0] - dvv[0] < GATE2) {
                    int i = atomicAdd(gcnt2, 1);
                    list2[i] = pxid[j];
                }
            }
            __syncthreads();
        }
    }
}

// Stage-3: exact fp64 full rescan, 1 px/pass (list2 is tiny).
__global__ __launch_bounds__(256) void recheck64(
        const float* __restrict__ x,
        const float* __restrict__ cct,
        const double* __restrict__ csqd,
        const int*   __restrict__ list2,
        const int*   __restrict__ gcnt2,
        int* __restrict__ out)
{
    __shared__ float  xcol[NC];        // 2KB
    __shared__ double part[4][NK];     // 16KB
    __shared__ double dvv[256];
    __shared__ int    dii[256];

    const int tid  = threadIdx.x;
    const int w    = tid >> 6;
    const int lane = tid & 63;
    const int n    = gcnt2[0];

    for (int idx = blockIdx.x; idx < n; idx += gridDim.x) {
        const int px = list2[idx];
        #pragma unroll
        for (int r = 0; r < 2; ++r) {
            const int c = tid + r * 256;
            xcol[c] = x[(size_t)(px >> 12) * (NC * NHW) + (size_t)c * NHW + (px & (NHW - 1))];
        }
        __syncthreads();

        double a[8] = {};
        const float4* cp = (const float4*)(cct + (size_t)(w * 128) * NK) + lane * 2;
        for (int c0 = 0; c0 < 128; ++c0) {
            const float4 cv0 = cp[0];
            const float4 cv1 = cp[1];
            cp += NK / 4;
            const double xv = (double)xcol[w * 128 + c0];
            const double ck[8] = {(double)cv0.x, (double)cv0.y, (double)cv0.z, (double)cv0.w,
                                  (double)cv1.x, (double)cv1.y, (double)cv1.z, (double)cv1.w};
            #pragma unroll
            for (int q = 0; q < 8; ++q) a[q] = fma(xv, ck[q], a[q]);
        }
        #pragma unroll
        for (int q = 0; q < 8; ++q) part[w][lane * 8 + q] = a[q];
        __syncthreads();

        double bd = 1e300;
        int bi = 1 << 30;
        #pragma unroll
        for (int r = 0; r < 2; ++r) {
            const int k = tid + r * 256;
            const double cross = part[0][k] + part[1][k] + part[2][k] + part[3][k];
            const double d = fma(-2.0, cross, csqd[k]);
            if (d < bd || (d == bd && k < bi)) { bd = d; bi = k; }
        }
        dvv[tid] = bd; dii[tid] = bi;
        __syncthreads();
        for (int s = 128; s > 0; s >>= 1) {
            if (tid < s) {
                const double ov = dvv[tid + s]; const int oi = dii[tid + s];
                if (ov < dvv[tid] || (ov == dvv[tid] && oi < dii[tid])) {
                    dvv[tid] = ov; dii[tid] = oi;
                }
            }
            __syncthreads();
        }
        if (tid == 0) out[px] = dii[0];
        __syncthreads();
    }
}

extern "C" void kernel_launch(void* const* d_in, const int* in_sizes, int n_in,
                              void* d_out, int out_size, void* d_ws, size_t ws_size,
                              hipStream_t stream) {
    const float* x  = (const float*)d_in[0];   // (16, 512, 64, 64) f32
    const float* cc = (const float*)d_in[1];   // (1, 512, 512, 1, 1) f32 -> [k][c]
    int* out = (int*)d_out;                    // (16, 1, 64, 64) int32

    double* csqd  = (double*)d_ws;                        // 512 doubles (4KB)
    float*  csqf  = (float*)(csqd + NK);                  // 512 floats (2KB)
    float*  shalf = csqf + NK;                            // 512 floats (2KB)
    u16*    wcc   = (u16*)(shalf + NK);                   // 512KB frag-ordered fp16
    float*  cct   = (float*)(wcc + 32 * 2 * 8 * 64 * 8);  // 1MB transposed centers
    float*  cbv   = cct + (size_t)NC * NK;                // 2*NPX floats
    float*  csv   = cbv + 2 * NPX;                        // 2*NPX floats
    int*    ckk   = (int*)(csv + 2 * NPX);                // 2*NPX ints
    int*    glist = ckk + 2 * NPX;                        // NPX ints
    int*    list2 = glist + NPX;                          // NPX ints
    int*    gcnt  = list2 + NPX;                          // 1 int
    int*    gcnt2 = gcnt + 1;                             // 1 int

    prep_pack<<<NK, 64, 0, stream>>>(cc, wcc, shalf, csqd, csqf, cct, gcnt, gcnt2);
    codebook_mfma<<<(NPX / 64) * 2, 256, 0, stream>>>(x, wcc, shalf, cbv, csv, ckk);
    merge<<<NPX / 256, 256, 0, stream>>>(cbv, csv, ckk, out, glist, gcnt);
    recheck32<<<768, 256, 0, stream>>>(x, cct, csqf, glist, gcnt, out, list2, gcnt2);
    recheck64<<<256, 256, 0, stream>>>(x, cct, csqd, list2, gcnt2, out);
}